// Round 15
// baseline (559.054 us; speedup 1.0000x reference)
//
#include <hip/hip_runtime.h>
#include <math.h>

#define EPSV 1e-5f
#define SCALE_W 0.0441941738241592f   /* 1/sqrt(512) */
#define GAIN_R 1.4142135623730951f    /* sqrt(2) */

typedef __attribute__((ext_vector_type(8))) short bf16x8;
typedef __attribute__((ext_vector_type(4))) float f32x4;
typedef __attribute__((ext_vector_type(4))) unsigned int u32x4;

static __device__ __forceinline__ unsigned short f2bf(float f) {
  union { float f; unsigned int u; } v; v.f = f;
  unsigned int r = v.u + 0x7FFFu + ((v.u >> 16) & 1u);   // RNE
  return (unsigned short)(r >> 16);
}

// packed f32->bf16 (RNE): lo -> low16, hi -> high16
static __device__ __forceinline__ unsigned int cvtpk(float lo, float hi) {
  unsigned int r;
  asm("v_cvt_pk_bf16_f32 %0, %1, %2" : "=v"(r) : "v"(lo), "v"(hi));
  return r;
}

#define GLD_LDS16(gsrc, ldst)                                                                      \
  __builtin_amdgcn_global_load_lds((const __attribute__((address_space(1))) unsigned int*)(gsrc),  \
                                   (__attribute__((address_space(3))) unsigned int*)(ldst), 16, 0, 0)

// lgkm-only barrier (epilogue only): does NOT drain vmcnt
#define LBAR() do {                                          \
  asm volatile("s_waitcnt lgkmcnt(0)" ::: "memory");         \
  __builtin_amdgcn_sched_barrier(0);                         \
  __builtin_amdgcn_s_barrier();                              \
  __builtin_amdgcn_sched_barrier(0);                         \
} while (0)

#define VMCNT(N) do {                                        \
  asm volatile("s_waitcnt vmcnt(" #N ")" ::: "memory");      \
  __builtin_amdgcn_sched_barrier(0);                         \
} while (0)

// ---------------- pre-kernel: b = expmap0(bias), y2 = ||b||^2 ----------------
__global__ void bias_expmap_k(const float* __restrict__ bias, float* __restrict__ bexp,
                              float* __restrict__ y2out) {
  __shared__ float part[8];
  int t = threadIdx.x;
  float bv = bias[t];
  float s = bv * bv;
  s += __shfl_xor(s, 1);  s += __shfl_xor(s, 2);  s += __shfl_xor(s, 4);
  s += __shfl_xor(s, 8);  s += __shfl_xor(s, 16); s += __shfl_xor(s, 32);
  if ((t & 63) == 0) part[t >> 6] = s;
  __syncthreads();
  float tot = 0.f;
#pragma unroll
  for (int i = 0; i < 8; ++i) tot += part[i];
  float un = fmaxf(sqrtf(tot), EPSV);
  float th = tanhf(un);
  bexp[t] = th * bv / un;
  if (t == 0) *y2out = th * th;
}

// ---------------- pre-kernel: pack weight -> bf16 fragments, SCALE baked ----
// chunk (ks*32 + colhi): lane (lgr*16+l15) holds W[col=colhi*16+l15][k=ks*32+lgr*8+j].
__global__ void pack_weight_k(const float* __restrict__ w, unsigned short* __restrict__ wsB) {
  int e = blockIdx.x * 256 + threadIdx.x;   // 0..262143
  int o = e >> 9;          // output col (row of W)
  int k = e & 511;
  int ks = k >> 5, kk = k & 31;
  int lgr = kk >> 3, j = kk & 7;
  int colhi = o >> 4, l15 = o & 15;
  int dst = ((ks * 32 + colhi) * 64 + lgr * 16 + l15) * 8 + j;
  wsB[dst] = f2bf(w[e] * SCALE_W);
}

// ---------------- main kernel: NO per-step barriers ----------------
// 256 thr / 4 waves. BM=64, BN=512. Wave tile 64x128 (mf=4, nf=8, acc=128).
// A (x): direct per-lane global loads in MFMA fragment layout (identical across
//   waves -> 4x redundant, L2-served), converted in-register. No LDS for A.
// B (W): per-wave-PRIVATE gload_lds dbuf (8 chunks/wave/step) -> no cross-wave
//   LDS dependency -> K-loop has ZERO s_barrier. One uniform VMCNT(16)/step.
// Cross-wave sync only in the per-tile epilogue (5 lgkm barriers / 16 steps).
#define SCR 65536        /* 4 waves * 2 bufs * 8 KB */
#define SMEMSZ 70400

__global__ __launch_bounds__(256, 2)
void hyp_nobar_k(const float* __restrict__ x, const unsigned short* __restrict__ wsB,
                 const float* __restrict__ bexp, const float* __restrict__ y2p,
                 float* __restrict__ out, int tilesPerBlk) {
  extern __shared__ char smem[];
  const int tid  = threadIdx.x;
  const int lane = tid & 63;
  const int wave = tid >> 6;       // 0..3 : col group (128 cols each)
  const int l15  = lane & 15;
  const int lgr  = lane >> 4;      // 0..3

  char* bbase = smem + wave * 16384;               // private: [2][8192]
  float* xn2      = (float*)(smem + SCR);          // [64] (reused as tml)
  float* pS2      = (float*)(smem + SCR + 256);    // [64][4] (reused as pN2)
  float* pSB      = (float*)(smem + SCR + 1280);   // [64][4]
  float* g12      = (float*)(smem + SCR + 2304);   // [64][2]
  float* bexp_lds = (float*)(smem + SCR + 2816);   // [512]

  f32x4 acc[4][8];
#pragma unroll
  for (int mf = 0; mf < 4; ++mf)
#pragma unroll
    for (int nf = 0; nf < 8; ++nf) acc[mf][nf] = f32x4{0.f, 0.f, 0.f, 0.f};

  const long base = (long)blockIdx.x * tilesPerBlk;
  const int U = tilesPerBlk * 16;
  // per-lane x base for fragment loads: row (base*64 + mf*16 + l15), k (t*32 + lgr*8)
  const float* xlp = x + ((size_t)base * 64 + l15) * 512 + lgr * 8;

  const float y2v = *y2p;   // uniform -> s_load (lgkm, not in vm queue)

  // prologue: bexp -> LDS (read after epilogue's first LBAR)
  {
    float2 bc = *(const float2*)(bexp + tid * 2);
    *(float2*)(bexp_lds + tid * 2) = bc;
  }

  float xss[4] = {0.f, 0.f, 0.f, 0.f};
  f32x4 xb[2][4][2];   // [bank][mf][half], bank = t&1

  // issue B(0) -> buf 0 ; x(0) -> bank 0          queue: [B0 8, x0 8]
#pragma unroll
  for (int i = 0; i < 8; ++i)
    GLD_LDS16((const char*)wsB + (wave * 8 + i) * 1024 + lane * 16, bbase + i * 1024);
#pragma unroll
  for (int mf = 0; mf < 4; ++mf) {
    const float* p = xlp + mf * 8192;
    xb[0][mf][0] = *(const f32x4*)p;
    xb[0][mf][1] = *(const f32x4*)(p + 4);
  }

#pragma unroll 2
  for (int t = 0; t < U; ++t) {
    const int cur = t & 1, nxt = cur ^ 1;
    const bool epi = ((t & 15) == 15);

    // 1. issue B(t+1) -> private buf nxt (W K-slice wraps per tile)
    {
      const char* bs = (const char*)wsB + (size_t)((t + 1) & 15) * 32768;
      char* bd = bbase + nxt * 8192;
#pragma unroll
      for (int i = 0; i < 8; ++i)
        GLD_LDS16(bs + (wave * 8 + i) * 1024 + lane * 16, bd + i * 1024);
    }
    // 2. issue x(t+1) fragments -> bank nxt
    {
      int gu = t + 1; if (gu >= U) gu = U - 1;
      const float* p0 = xlp + (size_t)(gu >> 4) * 32768 + (gu & 15) * 32;
#pragma unroll
      for (int mf = 0; mf < 4; ++mf) {
        xb[nxt][mf][0] = *(const f32x4*)(p0 + mf * 8192);
        xb[nxt][mf][1] = *(const f32x4*)(p0 + mf * 8192 + 4);
      }
    }
    // 3. uniform drain: completes B(t) (own LDS chunks) + x(t) (+ prior epi stores);
    //    leaves [B(t+1)8, x(t+1)8] = 16 newest in flight. No barrier.
    VMCNT(16);

    // 4. convert x(t) -> bf16 fragments; accumulate per-row ||x||^2 (fp32)
    u32x4 xf[4];
#pragma unroll
    for (int mf = 0; mf < 4; ++mf) {
      f32x4 a = xb[cur][mf][0], b = xb[cur][mf][1];
      xss[mf] += a[0]*a[0] + a[1]*a[1] + a[2]*a[2] + a[3]*a[3]
               + b[0]*b[0] + b[1]*b[1] + b[2]*b[2] + b[3]*b[3];
      xf[mf][0] = cvtpk(a[0], a[1]); xf[mf][1] = cvtpk(a[2], a[3]);
      xf[mf][2] = cvtpk(b[0], b[1]); xf[mf][3] = cvtpk(b[2], b[3]);
    }

    // 5. B fragments (two 4-reg groups) + MFMA — wave-local, compiler-scheduled
    {
      const char* bb = bbase + cur * 8192 + lane * 16;
      bf16x8 wf[4];
      __builtin_amdgcn_s_setprio(1);
#pragma unroll
      for (int nf = 0; nf < 4; ++nf) wf[nf] = *(const bf16x8*)(bb + nf * 1024);
#pragma unroll
      for (int mf = 0; mf < 4; ++mf) {
        const bf16x8 xv = __builtin_bit_cast(bf16x8, xf[mf]);
#pragma unroll
        for (int nf = 0; nf < 4; ++nf)
          acc[mf][nf] = __builtin_amdgcn_mfma_f32_16x16x32_bf16(wf[nf], xv, acc[mf][nf], 0, 0, 0);
      }
#pragma unroll
      for (int nf = 0; nf < 4; ++nf) wf[nf] = *(const bf16x8*)(bb + (4 + nf) * 1024);
#pragma unroll
      for (int mf = 0; mf < 4; ++mf) {
        const bf16x8 xv = __builtin_bit_cast(bf16x8, xf[mf]);
#pragma unroll
        for (int nf = 0; nf < 4; ++nf)
          acc[mf][4 + nf] = __builtin_amdgcn_mfma_f32_16x16x32_bf16(wf[nf], xv, acc[mf][4 + nf], 0, 0, 0);
      }
      __builtin_amdgcn_s_setprio(0);
    }

    // 6. per-tile epilogue (only cross-wave section; 5 lgkm barriers / 16 steps)
    if (epi) {
      const long trow = (base + (t >> 4)) * 64;

      // row ||x||^2: reduce over lgr groups (k-slices)
#pragma unroll
      for (int mf = 0; mf < 4; ++mf) {
        float v = xss[mf];
        v += __shfl_xor(v, 16); v += __shfl_xor(v, 32);
        if (lane < 16) xn2[mf * 16 + l15] = v;
        xss[mf] = 0.f;
      }

      f32x4 bvv[8];
#pragma unroll
      for (int nf = 0; nf < 8; ++nf)
        bvv[nf] = *(const f32x4*)(bexp_lds + wave * 128 + nf * 16 + lgr * 4);

      float s2[4], sb[4];
#pragma unroll
      for (int mf = 0; mf < 4; ++mf) {
        s2[mf] = 0.f; sb[mf] = 0.f;
#pragma unroll
        for (int nf = 0; nf < 8; ++nf)
#pragma unroll
          for (int j = 0; j < 4; ++j) {
            float v = acc[mf][nf][j];
            s2[mf] += v * v;
            sb[mf] += v * bvv[nf][j];
          }
        s2[mf] += __shfl_xor(s2[mf], 16); s2[mf] += __shfl_xor(s2[mf], 32);
        sb[mf] += __shfl_xor(sb[mf], 16); sb[mf] += __shfl_xor(sb[mf], 32);
      }
      if (lane < 16) {
#pragma unroll
        for (int mf = 0; mf < 4; ++mf) {
          pS2[(mf * 16 + l15) * 4 + wave] = s2[mf];
          pSB[(mf * 16 + l15) * 4 + wave] = sb[mf];
        }
      }
      LBAR();

      if (tid < 64) {
        int r = tid;
        float S2 = 0.f, SB = 0.f;
#pragma unroll
        for (int i = 0; i < 4; ++i) { S2 += pS2[r * 4 + i]; SB += pSB[r * 4 + i]; }
        float xn  = fmaxf(sqrtf(xn2[r]), EPSV);
        float mxn = fmaxf(sqrtf(S2), EPSV);
        float f = tanhf((mxn / xn) * atanhf(fminf(xn, 1.f - EPSV))) / mxn;  // mv = f*mx
        float xy = f * SB;
        float x2 = f * f * S2;
        float den = 1.f + 2.f * xy + x2 * y2v + EPSV;
        float g1 = (1.f + 2.f * xy + y2v) * f / den;   // coeff on mx
        float g2 = (1.f - x2) / den;                   // coeff on b
        float n1sq = g1 * g1 * S2 + 2.f * g1 * g2 * SB + g2 * g2 * y2v;
        float n1 = fmaxf(sqrtf(fmaxf(n1sq, 0.f)), EPSV);
        if (n1 > 0.999f) { float sc = 0.999f / n1; g1 *= sc; g2 *= sc; }   // project()
        g12[r * 2] = g1; g12[r * 2 + 1] = g2;
      }
      LBAR();

      float n2p[4];
#pragma unroll
      for (int mf = 0; mf < 4; ++mf) {
        float g1 = g12[(mf * 16 + l15) * 2], g2 = g12[(mf * 16 + l15) * 2 + 1];
        n2p[mf] = 0.f;
#pragma unroll
        for (int nf = 0; nf < 8; ++nf)
#pragma unroll
          for (int j = 0; j < 4; ++j) {
            float v = g1 * acc[mf][nf][j] + g2 * bvv[nf][j];
            v = v > 0.f ? v : 0.2f * v;
            acc[mf][nf][j] = v;
            n2p[mf] += v * v;
          }
        n2p[mf] += __shfl_xor(n2p[mf], 16); n2p[mf] += __shfl_xor(n2p[mf], 32);
      }
      if (lane < 16) {
#pragma unroll
        for (int mf = 0; mf < 4; ++mf) pS2[(mf * 16 + l15) * 4 + wave] = n2p[mf];  // pN2
      }
      LBAR();

      if (tid < 64) {
        int r = tid;
        float sn = 0.f;
#pragma unroll
        for (int i = 0; i < 4; ++i) sn += pS2[r * 4 + i];
        float n2 = fmaxf(sqrtf(sn), EPSV);
        xn2[r] = tanhf(GAIN_R * atanhf(fminf(n2, 1.f - EPSV))) / n2;  // tml
      }
      LBAR();

      // stores (32 x 16B/thread; folded into next step's VMCNT(16) drain)
#pragma unroll
      for (int mf = 0; mf < 4; ++mf) {
        float tm = xn2[mf * 16 + l15];
#pragma unroll
        for (int nf = 0; nf < 8; ++nf) {
          f32x4 o = acc[mf][nf];
          o[0] *= tm; o[1] *= tm; o[2] *= tm; o[3] *= tm;
          *(f32x4*)(out + (size_t)(trow + mf * 16 + l15) * 512 +
                    wave * 128 + nf * 16 + lgr * 4) = o;
          acc[mf][nf] = f32x4{0.f, 0.f, 0.f, 0.f};
        }
      }
      // guard: no wave may overwrite xn2/pS2 (next tile) while others still read tml
      LBAR();
    }
  }
}

extern "C" void kernel_launch(void* const* d_in, const int* in_sizes, int n_in,
                              void* d_out, int out_size, void* d_ws, size_t ws_size,
                              hipStream_t stream) {
  const float* x    = (const float*)d_in[0];
  const float* w    = (const float*)d_in[1];
  const float* bias = (const float*)d_in[2];
  float* out = (float*)d_out;

  unsigned short* wsB = (unsigned short*)d_ws;                 // 524288 B
  float* bexp = (float*)((char*)d_ws + 524288);                // 2048 B
  float* y2p  = (float*)((char*)d_ws + 524288 + 2048);         // 4 B

  bias_expmap_k<<<dim3(1), dim3(512), 0, stream>>>(bias, bexp, y2p);
  pack_weight_k<<<dim3(1024), dim3(256), 0, stream>>>(w, wsB);

  const int nrows  = in_sizes[0] / 512;      // 131072
  const int ntiles = nrows / 64;             // 2048
  const int nblk   = 512;                    // 2 blocks/CU
  const int tpb    = ntiles / nblk;          // 4
  hyp_nobar_k<<<dim3(nblk), dim3(256), SMEMSZ, stream>>>(x, wsB, bexp, y2p, out, tpb);
}

// Round 16
// 175.186 us; speedup vs baseline: 3.1912x; 3.1912x over previous
//
#include <hip/hip_runtime.h>
#include <math.h>

#define EPSV 1e-5f
#define SCALE_W 0.0441941738241592f   /* 1/sqrt(512) */
#define GAIN_R 1.4142135623730951f    /* sqrt(2) */

typedef __attribute__((ext_vector_type(8))) short bf16x8;
typedef __attribute__((ext_vector_type(4))) float f32x4;
typedef __attribute__((ext_vector_type(4))) unsigned int u32x4;

static __device__ __forceinline__ unsigned short f2bf(float f) {
  union { float f; unsigned int u; } v; v.f = f;
  unsigned int r = v.u + 0x7FFFu + ((v.u >> 16) & 1u);   // RNE
  return (unsigned short)(r >> 16);
}

// packed f32->bf16 (RNE): lo -> low16, hi -> high16 (same rounding as f2bf)
static __device__ __forceinline__ unsigned int cvtpk(float lo, float hi) {
  unsigned int r;
  asm("v_cvt_pk_bf16_f32 %0, %1, %2" : "=v"(r) : "v"(lo), "v"(hi));
  return r;
}

#define GLD_LDS16(gsrc, ldst)                                                                      \
  __builtin_amdgcn_global_load_lds((const __attribute__((address_space(1))) unsigned int*)(gsrc),  \
                                   (__attribute__((address_space(3))) unsigned int*)(ldst), 16, 0, 0)

// lgkm-only barrier: does NOT drain vmcnt -> in-flight loads/gload_lds survive
#define LBAR() do {                                          \
  asm volatile("s_waitcnt lgkmcnt(0)" ::: "memory");         \
  __builtin_amdgcn_sched_barrier(0);                         \
  __builtin_amdgcn_s_barrier();                              \
  __builtin_amdgcn_sched_barrier(0);                         \
} while (0)

#define VMCNT(N) do {                                        \
  asm volatile("s_waitcnt vmcnt(" #N ")" ::: "memory");      \
  __builtin_amdgcn_sched_barrier(0);                         \
} while (0)

// ---------------- pre-kernel: b = expmap0(bias), y2 = ||b||^2 ----------------
__global__ void bias_expmap_k(const float* __restrict__ bias, float* __restrict__ bexp,
                              float* __restrict__ y2out) {
  __shared__ float part[8];
  int t = threadIdx.x;
  float bv = bias[t];
  float s = bv * bv;
  s += __shfl_xor(s, 1);  s += __shfl_xor(s, 2);  s += __shfl_xor(s, 4);
  s += __shfl_xor(s, 8);  s += __shfl_xor(s, 16); s += __shfl_xor(s, 32);
  if ((t & 63) == 0) part[t >> 6] = s;
  __syncthreads();
  float tot = 0.f;
#pragma unroll
  for (int i = 0; i < 8; ++i) tot += part[i];
  float un = fmaxf(sqrtf(tot), EPSV);
  float th = tanhf(un);
  bexp[t] = th * bv / un;
  if (t == 0) *y2out = th * th;
}

// ---------------- pre-kernel: pack weight -> bf16 fragments, SCALE baked ----
// chunk = (ks*32 + colhi): 64 lanes x 16B; lane (lgr*16+l15) holds
// W[col=colhi*16+l15][k=ks*32+lgr*8+j], j=0..7.
__global__ void pack_weight_k(const float* __restrict__ w, unsigned short* __restrict__ wsB) {
  int e = blockIdx.x * 256 + threadIdx.x;   // 0..262143
  int o = e >> 9;          // output col (row of W)
  int k = e & 511;
  int ks = k >> 5, kk = k & 31;
  int lgr = kk >> 3, j = kk & 7;
  int colhi = o >> 4, l15 = o & 15;
  int dst = ((ks * 32 + colhi) * 64 + lgr * 16 + l15) * 8 + j;
  wsB[dst] = f2bf(w[e] * SCALE_W);
}

// ---------------- main fused kernel (R8 structure — session optimum) ----------------
// 256 thr / 4 waves, BM=64, BN=512, BK=32. Wave tile 64x128 (mf=4, nf=8).
// A: reg-staged fp32->bf16 (cvt_pk), dbuf [64 rows][80 B]. B: gload_lds dbuf 2x32KB.
// One lgkm barrier per K-step; counted vmcnt keeps 10 loads in flight.
#define RB 80
#define ABUF 5120        /* 64*80 */
#define BOFF 10240
#define BBUF 32768
#define SCR 75776
#define SMEMSZ 80896

__global__ __launch_bounds__(256, 2)
void hyp_main_k(const float* __restrict__ x, const unsigned short* __restrict__ wsB,
                const float* __restrict__ bexp, const float* __restrict__ y2p,
                float* __restrict__ out, int tilesPerBlk) {
  extern __shared__ char smem[];
  const int tid  = threadIdx.x;
  const int lane = tid & 63;
  const int wave = tid >> 6;       // 0..3 : col group (128 cols each)
  const int l15  = lane & 15;
  const int lgr  = lane >> 4;      // 0..3
  const int srow = tid >> 2;       // stage row 0..63
  const int sq   = tid & 3;        // k-subgroup (8 floats)

  float* xn2      = (float*)(smem + SCR);          // [64] (reused as tml)
  float* pS2      = (float*)(smem + SCR + 256);    // [64][4] (reused as pN2)
  float* pSB      = (float*)(smem + SCR + 1280);   // [64][4]
  float* g12      = (float*)(smem + SCR + 2304);   // [64][2]
  float* bexp_lds = (float*)(smem + SCR + 2816);   // [512]
  float* y2l      = (float*)(smem + SCR + 4864);   // [1]

  f32x4 acc[4][8];
#pragma unroll
  for (int mf = 0; mf < 4; ++mf)
#pragma unroll
    for (int nf = 0; nf < 8; ++nf) acc[mf][nf] = f32x4{0.f, 0.f, 0.f, 0.f};

  const long base = (long)blockIdx.x * tilesPerBlk;
  const int U = tilesPerBlk * 16;
  float xss = 0.f;
  f32x4 stA, stB;

  // ---- prologue ----
  {
    float2 bc = *(const float2*)(bexp + tid * 2);
    *(float2*)(bexp_lds + tid * 2) = bc;
    if (tid == 0) *y2l = *y2p;
    // A(0): rows base*64+srow, k = sq*8..sq*8+7
    const float* p = x + (size_t)(base * 64 + srow) * 512 + sq * 8;
    f32x4 a = *(const f32x4*)p;
    f32x4 b = *(const f32x4*)(p + 4);
    xss += a[0]*a[0] + a[1]*a[1] + a[2]*a[2] + a[3]*a[3];
    xss += b[0]*b[0] + b[1]*b[1] + b[2]*b[2] + b[3]*b[3];
    u32x4 pk;
    pk[0] = cvtpk(a[0], a[1]); pk[1] = cvtpk(a[2], a[3]);
    pk[2] = cvtpk(b[0], b[1]); pk[3] = cvtpk(b[2], b[3]);
    *(u32x4*)(smem + srow * RB + sq * 16) = pk;   // A buf 0
    // B(0) -> B buf 0 (queue after this: [B0 x8])
#pragma unroll
    for (int i = 0; i < 8; ++i)
      GLD_LDS16((const char*)wsB + (wave * 8 + i) * 1024 + lane * 16,
                smem + BOFF + (wave * 8 + i) * 1024);
  }
  LBAR();

#pragma unroll 1
  for (int t = 0; t < U; ++t) {
    const int cur = t & 1, nxt = cur ^ 1;

    // 1. issue A(t+1) loads (2)
    {
      const int gu = (t + 1 < U) ? t + 1 : U - 1;
      const float* p = x + (size_t)((base + (gu >> 4)) * 64 + srow) * 512 + (gu & 15) * 32 + sq * 8;
      stA = *(const f32x4*)p;
      stB = *(const f32x4*)(p + 4);
    }
    // 2. issue B(t+1) gloads (8) -> B buf nxt
    {
      const char* bs = (const char*)wsB + (size_t)((t + 1) & 15) * 32768;
      char* bd = smem + BOFF + nxt * BBUF;
#pragma unroll
      for (int i = 0; i < 8; ++i)
        GLD_LDS16(bs + (wave * 8 + i) * 1024 + lane * 16, bd + (wave * 8 + i) * 1024);
    }
    // 3. drain B(t) only (queue: [B(t)8, A(t+1)2, B(t+1)8]; +ST32 right after epilogue)
    if (t > 0 && (t & 15) == 0) { VMCNT(42); } else { VMCNT(10); }

    // 4. fragments + MFMA (swapped operands: store row = mf*16+l15)
    {
      const char* ab = smem + cur * ABUF + l15 * RB + lgr * 16;
      const char* bb = smem + BOFF + cur * BBUF + (wave * 8) * 1024 + lane * 16;
      bf16x8 xf[4], wf[8];
#pragma unroll
      for (int mf = 0; mf < 4; ++mf) xf[mf] = *(const bf16x8*)(ab + mf * (16 * RB));
#pragma unroll
      for (int nf = 0; nf < 8; ++nf) wf[nf] = *(const bf16x8*)(bb + nf * 1024);
      __builtin_amdgcn_s_setprio(1);
#pragma unroll
      for (int mf = 0; mf < 4; ++mf)
#pragma unroll
        for (int nf = 0; nf < 8; ++nf)
          acc[mf][nf] = __builtin_amdgcn_mfma_f32_16x16x32_bf16(wf[nf], xf[mf], acc[mf][nf], 0, 0, 0);
      __builtin_amdgcn_s_setprio(0);
    }

    // 5. fused hyperbolic epilogue (before pack: xss is still this tile's)
    if ((t & 15) == 15) {
      const long trow = (base + (t >> 4)) * 64;

      float xs = xss;
      xs += __shfl_xor(xs, 1); xs += __shfl_xor(xs, 2);
      if (sq == 0) xn2[srow] = xs;
      xss = 0.f;

      f32x4 bvv[8];
#pragma unroll
      for (int nf = 0; nf < 8; ++nf)
        bvv[nf] = *(const f32x4*)(bexp_lds + wave * 128 + nf * 16 + lgr * 4);

      float s2[4], sb[4];
#pragma unroll
      for (int mf = 0; mf < 4; ++mf) {
        s2[mf] = 0.f; sb[mf] = 0.f;
#pragma unroll
        for (int nf = 0; nf < 8; ++nf)
#pragma unroll
          for (int j = 0; j < 4; ++j) {
            float v = acc[mf][nf][j];
            s2[mf] += v * v;
            sb[mf] += v * bvv[nf][j];
          }
        s2[mf] += __shfl_xor(s2[mf], 16); s2[mf] += __shfl_xor(s2[mf], 32);
        sb[mf] += __shfl_xor(sb[mf], 16); sb[mf] += __shfl_xor(sb[mf], 32);
      }
      if (lane < 16) {
#pragma unroll
        for (int mf = 0; mf < 4; ++mf) {
          pS2[(mf * 16 + l15) * 4 + wave] = s2[mf];
          pSB[(mf * 16 + l15) * 4 + wave] = sb[mf];
        }
      }
      LBAR();

      if (tid < 64) {
        int r = tid;
        float S2 = 0.f, SB = 0.f;
#pragma unroll
        for (int i = 0; i < 4; ++i) { S2 += pS2[r * 4 + i]; SB += pSB[r * 4 + i]; }
        float y2s = *y2l;
        float xn  = fmaxf(sqrtf(xn2[r]), EPSV);
        float mxn = fmaxf(sqrtf(S2), EPSV);
        float f = tanhf((mxn / xn) * atanhf(fminf(xn, 1.f - EPSV))) / mxn;  // mv = f*mx
        float xy = f * SB;
        float x2 = f * f * S2;
        float den = 1.f + 2.f * xy + x2 * y2s + EPSV;
        float g1 = (1.f + 2.f * xy + y2s) * f / den;   // coeff on mx
        float g2 = (1.f - x2) / den;                   // coeff on b
        float n1sq = g1 * g1 * S2 + 2.f * g1 * g2 * SB + g2 * g2 * y2s;
        float n1 = fmaxf(sqrtf(fmaxf(n1sq, 0.f)), EPSV);
        if (n1 > 0.999f) { float sc = 0.999f / n1; g1 *= sc; g2 *= sc; }   // project()
        g12[r * 2] = g1; g12[r * 2 + 1] = g2;
      }
      LBAR();

      float n2p[4];
#pragma unroll
      for (int mf = 0; mf < 4; ++mf) {
        float g1 = g12[(mf * 16 + l15) * 2], g2 = g12[(mf * 16 + l15) * 2 + 1];
        n2p[mf] = 0.f;
#pragma unroll
        for (int nf = 0; nf < 8; ++nf)
#pragma unroll
          for (int j = 0; j < 4; ++j) {
            float v = g1 * acc[mf][nf][j] + g2 * bvv[nf][j];
            v = v > 0.f ? v : 0.2f * v;
            acc[mf][nf][j] = v;
            n2p[mf] += v * v;
          }
        n2p[mf] += __shfl_xor(n2p[mf], 16); n2p[mf] += __shfl_xor(n2p[mf], 32);
      }
      if (lane < 16) {
#pragma unroll
        for (int mf = 0; mf < 4; ++mf) pS2[(mf * 16 + l15) * 4 + wave] = n2p[mf];  // pN2
      }
      LBAR();

      if (tid < 64) {
        int r = tid;
        float sn = 0.f;
#pragma unroll
        for (int i = 0; i < 4; ++i) sn += pS2[r * 4 + i];
        float n2 = fmaxf(sqrtf(sn), EPSV);
        xn2[r] = tanhf(GAIN_R * atanhf(fminf(n2, 1.f - EPSV))) / n2;  // tml
      }
      LBAR();

      // stores (32 x 16B per thread; they enter the vmcnt queue -> ledger above)
#pragma unroll
      for (int mf = 0; mf < 4; ++mf) {
        float tm = xn2[mf * 16 + l15];
#pragma unroll
        for (int nf = 0; nf < 8; ++nf) {
          f32x4 o = acc[mf][nf];
          o[0] *= tm; o[1] *= tm; o[2] *= tm; o[3] *= tm;
          *(f32x4*)(out + (size_t)(trow + mf * 16 + l15) * 512 +
                    wave * 128 + nf * 16 + lgr * 4) = o;
          acc[mf][nf] = f32x4{0.f, 0.f, 0.f, 0.f};
        }
      }
    }

    // 6. drain A(t+1) only (epilogue steps: +32 stores in queue)
    if ((t & 15) == 15) { VMCNT(40); } else { VMCNT(8); }

    // pack + ds_write A(t+1) -> A buf nxt
    {
      f32x4 a = stA, b = stB;
      xss += a[0]*a[0] + a[1]*a[1] + a[2]*a[2] + a[3]*a[3];
      xss += b[0]*b[0] + b[1]*b[1] + b[2]*b[2] + b[3]*b[3];
      u32x4 pk;
      pk[0] = cvtpk(a[0], a[1]); pk[1] = cvtpk(a[2], a[3]);
      pk[2] = cvtpk(b[0], b[1]); pk[3] = cvtpk(b[2], b[3]);
      *(u32x4*)(smem + nxt * ABUF + srow * RB + sq * 16) = pk;
    }
    // 7.
    LBAR();
  }
}

extern "C" void kernel_launch(void* const* d_in, const int* in_sizes, int n_in,
                              void* d_out, int out_size, void* d_ws, size_t ws_size,
                              hipStream_t stream) {
  const float* x    = (const float*)d_in[0];
  const float* w    = (const float*)d_in[1];
  const float* bias = (const float*)d_in[2];
  float* out = (float*)d_out;

  unsigned short* wsB = (unsigned short*)d_ws;                 // 524288 B
  float* bexp = (float*)((char*)d_ws + 524288);                // 2048 B
  float* y2p  = (float*)((char*)d_ws + 524288 + 2048);         // 4 B

  bias_expmap_k<<<dim3(1), dim3(512), 0, stream>>>(bias, bexp, y2p);
  pack_weight_k<<<dim3(1024), dim3(256), 0, stream>>>(w, wsB);

  const int nrows  = in_sizes[0] / 512;      // 131072
  const int ntiles = nrows / 64;             // 2048
  const int nblk   = 512;                    // 2 blocks/CU, persistent
  const int tpb    = ntiles / nblk;          // 4
  hyp_main_k<<<dim3(nblk), dim3(256), SMEMSZ, stream>>>(x, wsB, bexp, y2p, out, tpb);
}